// Round 1
// baseline (258.662 us; speedup 1.0000x reference)
//
#include <hip/hip_runtime.h>

#define BATCH_L 524288
#define NL 40
#define NXL 20
#define BLOCK 256

// One thread per row. Row = 160 B, all loads are aligned float4.
__global__ __launch_bounds__(BLOCK) void hybrid_loss_main(
    const float* __restrict__ pred,
    const float* __restrict__ targ,
    const float* __restrict__ ycur,
    double* __restrict__ sums)   // sums[0] = sum_dd, sums[1] = sum_pi
{
    const int row = blockIdx.x * BLOCK + threadIdx.x;
    const float4* __restrict__ p4 = reinterpret_cast<const float4*>(pred + (size_t)row * NL);
    const float4* __restrict__ y4 = reinterpret_cast<const float4*>(ycur + (size_t)row * NL);
    const float4* __restrict__ t4 = reinterpret_cast<const float4*>(targ + (size_t)row * NL);

    // Load the full prediction row into registers (needed for the periodic stencil).
    float p[NL];
#pragma unroll
    for (int j = 0; j < NL / 4; ++j) {
        float4 v = p4[j];
        p[4 * j + 0] = v.x; p[4 * j + 1] = v.y;
        p[4 * j + 2] = v.z; p[4 * j + 3] = v.w;
    }

    // Data-driven MSE over the first NXL elements.
    float sdd = 0.f;
#pragma unroll
    for (int j = 0; j < NXL / 4; ++j) {
        float4 v = t4[j];
        float d0 = p[4 * j + 0] - v.x;
        float d1 = p[4 * j + 1] - v.y;
        float d2 = p[4 * j + 2] - v.z;
        float d3 = p[4 * j + 3] - v.w;
        sdd += d0 * d0 + d1 * d1 + d2 * d2 + d3 * d3;
    }

    // Physics-informed residual: (p - y)/dt - [(p_{i+1} - p_{i-2}) * p_{i-1} - p_i + F]
    float spi = 0.f;
#pragma unroll
    for (int j = 0; j < NL / 4; ++j) {
        float4 v = y4[j];
        float yv[4] = {v.x, v.y, v.z, v.w};
#pragma unroll
        for (int k = 0; k < 4; ++k) {
            const int i = 4 * j + k;                 // compile-time after unroll
            float f = (p[(i + 1) % NL] - p[(i + NL - 2) % NL]) * p[(i + NL - 1) % NL]
                      - p[i] + 8.0f;
            float d = (p[i] - yv[k]) * 100.0f - f;   // 1/DT = 100
            spi += d * d;
        }
    }

    // Wave-64 shuffle reduction in double.
    double sd = (double)sdd, sp = (double)spi;
#pragma unroll
    for (int off = 32; off > 0; off >>= 1) {
        sd += __shfl_down(sd, off, 64);
        sp += __shfl_down(sp, off, 64);
    }

    __shared__ double lds[2 * (BLOCK / 64)];
    const int lane = threadIdx.x & 63;
    const int wave = threadIdx.x >> 6;
    if (lane == 0) { lds[2 * wave] = sd; lds[2 * wave + 1] = sp; }
    __syncthreads();
    if (threadIdx.x == 0) {
        double tsd = 0.0, tsp = 0.0;
#pragma unroll
        for (int w = 0; w < BLOCK / 64; ++w) { tsd += lds[2 * w]; tsp += lds[2 * w + 1]; }
        atomicAdd(&sums[0], tsd);
        atomicAdd(&sums[1], tsp);
    }
}

__global__ void hybrid_loss_finalize(const double* __restrict__ sums,
                                     float* __restrict__ out)
{
    const double l_dd = sums[0] / ((double)BATCH_L * NXL);
    const double l_pi = sums[1] / ((double)BATCH_L * NL);
    out[0] = (float)(l_dd + 0.1 * l_pi);
    out[1] = (float)l_dd;
    out[2] = (float)l_pi;
}

extern "C" void kernel_launch(void* const* d_in, const int* in_sizes, int n_in,
                              void* d_out, int out_size, void* d_ws, size_t ws_size,
                              hipStream_t stream) {
    const float* pred = (const float*)d_in[0];
    const float* targ = (const float*)d_in[1];
    const float* ycur = (const float*)d_in[2];
    double* sums = (double*)d_ws;
    float* out = (float*)d_out;

    // d_ws is poisoned with 0xAA before every timed launch — zero the accumulators.
    hipMemsetAsync(sums, 0, 2 * sizeof(double), stream);

    hybrid_loss_main<<<BATCH_L / BLOCK, BLOCK, 0, stream>>>(pred, targ, ycur, sums);
    hybrid_loss_finalize<<<1, 1, 0, stream>>>(sums, out);
}

// Round 2
// 246.340 us; speedup vs baseline: 1.0500x; 1.0500x over previous
//
#include <hip/hip_runtime.h>

#define BATCH_L 524288
#define NL 40
#define NXL 20
#define BLOCK 256
#define ROWS 128                       // rows per block
#define CHUNKS (ROWS * NL / 4)         // 1280 float4 per block
#define PER_T (CHUNKS / BLOCK)         // 5 float4 per thread
#define NBLOCKS (BATCH_L / ROWS)       // 4096

// Coalesced: lane loads consecutive float4s; pred staged in LDS for the
// periodic stencil; ycur folded into a = 101*p - 100*y - 8 in registers.
__global__ __launch_bounds__(BLOCK) void hybrid_loss_main(
    const float4* __restrict__ pred4,
    const float4* __restrict__ targ4,
    const float4* __restrict__ ycur4,
    double* __restrict__ partials)     // [NBLOCKS][2]
{
    __shared__ float4 lds_p4[CHUNKS];  // 20 KB
    float* lds_p = reinterpret_cast<float*>(lds_p4);
    __shared__ double lds_red[2 * (BLOCK / 64)];

    const int t = threadIdx.x;
    const size_t gbase = (size_t)blockIdx.x * CHUNKS;

    float P[PER_T][4];   // pred centers (needed as stencil neighbors in-chunk)
    float A[PER_T][4];   // 101*p - 100*y - 8
    float sdd = 0.f;

    // ---- Pass 1: fully coalesced global loads ----
#pragma unroll
    for (int k = 0; k < PER_T; ++k) {
        const int f = t + k * BLOCK;          // float4 index within block chunk
        const float4 pv = pred4[gbase + f];
        const float4 yv = ycur4[gbase + f];
        P[k][0] = pv.x; P[k][1] = pv.y; P[k][2] = pv.z; P[k][3] = pv.w;
        lds_p4[f] = pv;
        A[k][0] = 101.f * pv.x - 100.f * yv.x - 8.f;
        A[k][1] = 101.f * pv.y - 100.f * yv.y - 8.f;
        A[k][2] = 101.f * pv.z - 100.f * yv.z - 8.f;
        A[k][3] = 101.f * pv.w - 100.f * yv.w - 8.f;

        // data-driven MSE: chunk covers cols 4c..4c+3; all <20 iff c<5
        const int c = f % 10;
        if (c < 5) {
            const float4 tv = targ4[gbase + f];
            const float d0 = pv.x - tv.x;
            const float d1 = pv.y - tv.y;
            const float d2 = pv.z - tv.z;
            const float d3 = pv.w - tv.w;
            sdd += d0 * d0 + d1 * d1 + d2 * d2 + d3 * d3;
        }
    }
    __syncthreads();

    // ---- Pass 2: physics residual; 3 LDS reads per chunk for wrap neighbors ----
    float spi = 0.f;
#pragma unroll
    for (int k = 0; k < PER_T; ++k) {
        const int f = t + k * BLOCK;
        const int r = f / 10;                  // row within block
        const int c = f - 10 * r;              // float4-chunk within row
        const int base = r * NL;
        const int x = 4 * c;                   // column of element 0
        // p[i0-2], p[i0-1], p[i0+4] with periodic wrap (mod 40)
        const float pm2 = lds_p[base + ((c == 0) ? 38 : x - 2)];
        const float pm1 = lds_p[base + ((c == 0) ? 39 : x - 1)];
        const float pp4 = lds_p[base + ((c == 9) ? 0 : x + 4)];

        // d_i = a_i - (p_{i+1} - p_{i-2}) * p_{i-1}
        const float d0 = A[k][0] - (P[k][1] - pm2) * pm1;
        const float d1 = A[k][1] - (P[k][2] - pm1) * P[k][0];
        const float d2 = A[k][2] - (P[k][3] - P[k][0]) * P[k][1];
        const float d3 = A[k][3] - (pp4 - P[k][1]) * P[k][2];
        spi += d0 * d0 + d1 * d1 + d2 * d2 + d3 * d3;
    }

    // ---- Reduction: wave shuffle (double) -> LDS -> per-block partial ----
    double sd = (double)sdd, sp = (double)spi;
#pragma unroll
    for (int off = 32; off > 0; off >>= 1) {
        sd += __shfl_down(sd, off, 64);
        sp += __shfl_down(sp, off, 64);
    }
    const int lane = t & 63;
    const int wave = t >> 6;
    if (lane == 0) { lds_red[2 * wave] = sd; lds_red[2 * wave + 1] = sp; }
    __syncthreads();
    if (t == 0) {
        double tsd = 0.0, tsp = 0.0;
#pragma unroll
        for (int w = 0; w < BLOCK / 64; ++w) {
            tsd += lds_red[2 * w];
            tsp += lds_red[2 * w + 1];
        }
        partials[2 * blockIdx.x]     = tsd;   // plain stores: every slot written
        partials[2 * blockIdx.x + 1] = tsp;   // each launch -> no memset needed
    }
}

__global__ __launch_bounds__(256) void hybrid_loss_finalize(
    const double* __restrict__ partials, float* __restrict__ out)
{
    const double2* __restrict__ p2 = reinterpret_cast<const double2*>(partials);
    double sd = 0.0, sp = 0.0;
    for (int m = threadIdx.x; m < NBLOCKS; m += 256) {
        const double2 v = p2[m];
        sd += v.x; sp += v.y;
    }
#pragma unroll
    for (int off = 32; off > 0; off >>= 1) {
        sd += __shfl_down(sd, off, 64);
        sp += __shfl_down(sp, off, 64);
    }
    __shared__ double lds[8];
    const int lane = threadIdx.x & 63;
    const int wave = threadIdx.x >> 6;
    if (lane == 0) { lds[2 * wave] = sd; lds[2 * wave + 1] = sp; }
    __syncthreads();
    if (threadIdx.x == 0) {
        double tsd = 0.0, tsp = 0.0;
#pragma unroll
        for (int w = 0; w < 4; ++w) { tsd += lds[2 * w]; tsp += lds[2 * w + 1]; }
        const double l_dd = tsd / ((double)BATCH_L * NXL);
        const double l_pi = tsp / ((double)BATCH_L * NL);
        out[0] = (float)(l_dd + 0.1 * l_pi);
        out[1] = (float)l_dd;
        out[2] = (float)l_pi;
    }
}

extern "C" void kernel_launch(void* const* d_in, const int* in_sizes, int n_in,
                              void* d_out, int out_size, void* d_ws, size_t ws_size,
                              hipStream_t stream) {
    const float4* pred = (const float4*)d_in[0];
    const float4* targ = (const float4*)d_in[1];
    const float4* ycur = (const float4*)d_in[2];
    double* partials = (double*)d_ws;          // 4096 * 2 doubles = 64 KB
    float* out = (float*)d_out;

    hybrid_loss_main<<<NBLOCKS, BLOCK, 0, stream>>>(pred, targ, ycur, partials);
    hybrid_loss_finalize<<<1, 256, 0, stream>>>(partials, out);
}